// Round 1
// baseline (540.837 us; speedup 1.0000x reference)
//
#include <hip/hip_runtime.h>
#include <hip/hip_bf16.h>

constexpr int NN = 40000;
constexpr int NE = 640000;
constexpr int D  = 128;
constexpr int NG = 128;

// ---------------------------------------------------------------------------
// GEMM: out[n][d] = sum_k A[n][k] * W[d][k]   (h = A @ W^T)
// block = 256 threads = 16 row-quads x 16 d-slices(8); 64 rows per block.
// W^T staged in LDS with pitch 132 floats (16B aligned, conflict-benign).
// ---------------------------------------------------------------------------
__global__ __launch_bounds__(256)
void gemm_wt(const float* __restrict__ A, const float* __restrict__ W,
             float* __restrict__ out) {
  __shared__ float wt[128 * 132];
  const int tid = threadIdx.x;
  // stage W transposed: wt[k][d] = W[d][k]; read of W is coalesced (W[i])
  for (int i = tid; i < 128 * 128; i += 256) {
    const int d = i >> 7, k = i & 127;
    wt[k * 132 + d] = W[i];
  }
  __syncthreads();

  const int s  = tid & 15;          // d-slice index
  const int rq = tid >> 4;          // row-quad index
  const int n0 = blockIdx.x * 64 + rq * 4;
  const int d0 = s * 8;
  const float* ap = A + (size_t)n0 * D;

  float acc[4][8];
#pragma unroll
  for (int r = 0; r < 4; ++r)
#pragma unroll
    for (int j = 0; j < 8; ++j) acc[r][j] = 0.f;

  for (int kc = 0; kc < 32; ++kc) {
    float av[4][4];
#pragma unroll
    for (int r = 0; r < 4; ++r)
      *(float4*)av[r] = *(const float4*)(ap + (size_t)r * D + kc * 4);
#pragma unroll
    for (int kk = 0; kk < 4; ++kk) {
      const float* wrow = &wt[(kc * 4 + kk) * 132 + d0];
      const float4 w0 = *(const float4*)(wrow);
      const float4 w1 = *(const float4*)(wrow + 4);
#pragma unroll
      for (int r = 0; r < 4; ++r) {
        const float a = av[r][kk];
        acc[r][0] += a * w0.x; acc[r][1] += a * w0.y;
        acc[r][2] += a * w0.z; acc[r][3] += a * w0.w;
        acc[r][4] += a * w1.x; acc[r][5] += a * w1.y;
        acc[r][6] += a * w1.z; acc[r][7] += a * w1.w;
      }
    }
  }
#pragma unroll
  for (int r = 0; r < 4; ++r) {
    float* o = out + (size_t)(n0 + r) * D + d0;
    *(float4*)(o)     = make_float4(acc[r][0], acc[r][1], acc[r][2], acc[r][3]);
    *(float4*)(o + 4) = make_float4(acc[r][4], acc[r][5], acc[r][6], acc[r][7]);
  }
}

// ---------------------------------------------------------------------------
// CSR build: histogram of destination (col), exclusive scan, scatter fill.
// ---------------------------------------------------------------------------
__global__ void hist_k(const int* __restrict__ col, int* __restrict__ cnt) {
  const int e = blockIdx.x * blockDim.x + threadIdx.x;
  if (e < NE) atomicAdd(&cnt[col[e]], 1);
}

__global__ __launch_bounds__(1024)
void scan_k(const int* __restrict__ cnt, int* __restrict__ off,
            int* __restrict__ cur) {
  __shared__ int buf[1024];
  const int tid = threadIdx.x;
  constexpr int PER = (NN + 1023) / 1024;  // 40
  const int base = tid * PER;
  int T = 0;
  for (int j = 0; j < PER; ++j) {
    const int i = base + j;
    if (i < NN) T += cnt[i];
  }
  buf[tid] = T;
  __syncthreads();
  for (int sft = 1; sft < 1024; sft <<= 1) {
    const int v = (tid >= sft) ? buf[tid - sft] : 0;
    __syncthreads();
    buf[tid] += v;
    __syncthreads();
  }
  int run = buf[tid] - T;  // exclusive prefix
  for (int j = 0; j < PER; ++j) {
    const int i = base + j;
    if (i < NN) { off[i] = run; cur[i] = run; run += cnt[i]; }
  }
  if (tid == 1023) off[NN] = buf[1023];
}

__global__ void fill_k(const int* __restrict__ row, const int* __restrict__ col,
                       const float* __restrict__ w, int* __restrict__ cur,
                       int* __restrict__ esrc, float* __restrict__ ew) {
  const int e = blockIdx.x * blockDim.x + threadIdx.x;
  if (e < NE) {
    const int p = atomicAdd(&cur[col[e]], 1);
    esrc[p] = row[e];
    ew[p]   = w[e];
  }
}

// ---------------------------------------------------------------------------
// Gather (CSR) + PReLU: one wave per destination node; lane owns 2 columns.
// ---------------------------------------------------------------------------
__global__ __launch_bounds__(256)
void gather_prelu(const float* __restrict__ tmp, const int* __restrict__ off,
                  const int* __restrict__ esrc, const float* __restrict__ ew,
                  const float* __restrict__ aP, float* __restrict__ hout) {
  const int wid  = (blockIdx.x * 256 + threadIdx.x) >> 6;
  const int lane = threadIdx.x & 63;
  if (wid >= NN) return;
  const int lo = off[wid], hi = off[wid + 1];
  float ax = 0.f, ay = 0.f;
  int e = lo;
  for (; e + 1 < hi; e += 2) {
    const int   s0 = esrc[e],  s1 = esrc[e + 1];
    const float w0 = ew[e],    w1 = ew[e + 1];
    const float2 v0 = *(const float2*)(tmp + (size_t)s0 * D + lane * 2);
    const float2 v1 = *(const float2*)(tmp + (size_t)s1 * D + lane * 2);
    ax += v0.x * w0; ay += v0.y * w0;
    ax += v1.x * w1; ay += v1.y * w1;
  }
  if (e < hi) {
    const int s0 = esrc[e]; const float w0 = ew[e];
    const float2 v0 = *(const float2*)(tmp + (size_t)s0 * D + lane * 2);
    ax += v0.x * w0; ay += v0.y * w0;
  }
  const float alpha = aP[0];
  ax = ax >= 0.f ? ax : alpha * ax;
  ay = ay >= 0.f ? ay : alpha * ay;
  *(float2*)(hout + (size_t)wid * D + lane * 2) = make_float2(ax, ay);
}

// ---------------------------------------------------------------------------
// Graph pooling: block = 128 threads (one per column), grid = (NG, SPLIT).
// batch_indices sorted -> binary-search segment bounds, no per-row atomics.
// ---------------------------------------------------------------------------
constexpr int POOL_SPLIT = 8;

__device__ __forceinline__ int lbound(const int* a, int n, int key) {
  int lo = 0, hi = n;
  while (lo < hi) { const int m = (lo + hi) >> 1; if (a[m] < key) lo = m + 1; else hi = m; }
  return lo;
}

__global__ __launch_bounds__(128)
void pool_k(const float* __restrict__ h, const int* __restrict__ batch,
            float* __restrict__ hg, int layer) {
  const int g    = blockIdx.x;
  const int part = blockIdx.y;
  const int tid  = threadIdx.x;
  const int lo = lbound(batch, NN, g);
  const int hi = lbound(batch, NN, g + 1);
  float acc = 0.f;
  for (int n = lo + part; n < hi; n += POOL_SPLIT)
    acc += h[(size_t)n * D + tid];
  atomicAdd(&hg[(size_t)g * (3 * D) + layer * D + tid], acc);
}

// ---------------------------------------------------------------------------
extern "C" void kernel_launch(void* const* d_in, const int* in_sizes, int n_in,
                              void* d_out, int out_size, void* d_ws, size_t ws_size,
                              hipStream_t stream) {
  const float* feat    = (const float*)d_in[0];
  const float* eweight = (const float*)d_in[1];
  const float* W[3]    = {(const float*)d_in[2], (const float*)d_in[3], (const float*)d_in[4]};
  const float* a[3]    = {(const float*)d_in[5], (const float*)d_in[6], (const float*)d_in[7]};
  const int*   eidx    = (const int*)d_in[8];
  const int*   batch   = (const int*)d_in[9];
  const int*   erow = eidx;
  const int*   ecol = eidx + NE;

  char* ws = (char*)d_ws;
  float* tmp  = (float*)(ws);                 // 20,480,000 B
  float* hbuf = (float*)(ws + 20480000);      // 20,480,000 B
  int*   cnt  = (int*)(ws + 40960000);        //    163,840 B
  int*   off  = (int*)(ws + 41123840);        //    163,840 B
  int*   cur  = (int*)(ws + 41287680);        //    163,840 B
  int*   esrc = (int*)(ws + 41451520);        //  2,560,000 B
  float* ewr  = (float*)(ws + 44011520);      //  2,560,000 B  (end ~46.6 MB)

  float* hout = (float*)d_out;                 // NN x D
  float* hg   = hout + (size_t)NN * D;         // NG x 3D

  hipMemsetAsync(cnt, 0, (NN + 1) * sizeof(int), stream);
  hipMemsetAsync(hg, 0, (size_t)NG * 3 * D * sizeof(float), stream);

  hist_k<<<(NE + 255) / 256, 256, 0, stream>>>(ecol, cnt);
  scan_k<<<1, 1024, 0, stream>>>(cnt, off, cur);
  fill_k<<<(NE + 255) / 256, 256, 0, stream>>>(erow, ecol, eweight, cur, esrc, ewr);

  const float* in = feat;
  for (int l = 0; l < 3; ++l) {
    gemm_wt<<<NN / 64, 256, 0, stream>>>(in, W[l], tmp);
    float* dst = (l == 2) ? hout : hbuf;
    gather_prelu<<<(NN * 64) / 256, 256, 0, stream>>>(tmp, off, esrc, ewr, a[l], dst);
    pool_k<<<dim3(NG, POOL_SPLIT), 128, 0, stream>>>(dst, batch, hg, l);
    in = dst;
  }
}

// Round 2
// 445.703 us; speedup vs baseline: 1.2134x; 1.2134x over previous
//
#include <hip/hip_runtime.h>
#include <hip/hip_bf16.h>

constexpr int NN = 40000;
constexpr int NE = 640000;
constexpr int D  = 128;
constexpr int NG = 128;

// ---------------------------------------------------------------------------
// GEMM: out[n][d] = sum_k A[n][k] * W[d][k]   (h = A @ W^T)
// block = 256 threads = 16 row-quads x 16 d-slices(8); 64 rows per block.
// W^T staged in LDS with pitch 132 floats (16B aligned, conflict-benign).
// ---------------------------------------------------------------------------
__global__ __launch_bounds__(256)
void gemm_wt(const float* __restrict__ A, const float* __restrict__ W,
             float* __restrict__ out) {
  __shared__ float wt[128 * 132];
  const int tid = threadIdx.x;
  for (int i = tid; i < 128 * 128; i += 256) {
    const int d = i >> 7, k = i & 127;
    wt[k * 132 + d] = W[i];
  }
  __syncthreads();

  const int s  = tid & 15;          // d-slice index
  const int rq = tid >> 4;          // row-quad index
  const int n0 = blockIdx.x * 64 + rq * 4;
  const int d0 = s * 8;
  const float* ap = A + (size_t)n0 * D;

  float acc[4][8];
#pragma unroll
  for (int r = 0; r < 4; ++r)
#pragma unroll
    for (int j = 0; j < 8; ++j) acc[r][j] = 0.f;

  for (int kc = 0; kc < 32; ++kc) {
    float av[4][4];
#pragma unroll
    for (int r = 0; r < 4; ++r)
      *(float4*)av[r] = *(const float4*)(ap + (size_t)r * D + kc * 4);
#pragma unroll
    for (int kk = 0; kk < 4; ++kk) {
      const float* wrow = &wt[(kc * 4 + kk) * 132 + d0];
      const float4 w0 = *(const float4*)(wrow);
      const float4 w1 = *(const float4*)(wrow + 4);
#pragma unroll
      for (int r = 0; r < 4; ++r) {
        const float a = av[r][kk];
        acc[r][0] += a * w0.x; acc[r][1] += a * w0.y;
        acc[r][2] += a * w0.z; acc[r][3] += a * w0.w;
        acc[r][4] += a * w1.x; acc[r][5] += a * w1.y;
        acc[r][6] += a * w1.z; acc[r][7] += a * w1.w;
      }
    }
  }
#pragma unroll
  for (int r = 0; r < 4; ++r) {
    float* o = out + (size_t)(n0 + r) * D + d0;
    *(float4*)(o)     = make_float4(acc[r][0], acc[r][1], acc[r][2], acc[r][3]);
    *(float4*)(o + 4) = make_float4(acc[r][4], acc[r][5], acc[r][6], acc[r][7]);
  }
}

// ---------------------------------------------------------------------------
// CSR build: histogram of destination (col), 3-phase parallel scan, fill.
// ---------------------------------------------------------------------------
__global__ void hist_k(const int* __restrict__ col, int* __restrict__ cnt) {
  const int e = blockIdx.x * blockDim.x + threadIdx.x;
  if (e < NE) atomicAdd(&cnt[col[e]], 1);
}

constexpr int SCAN_B = 1024;
constexpr int SCAN_NB = (NN + SCAN_B - 1) / SCAN_B;  // 40

// phase 1: per-block local exclusive prefix (coalesced, 1 elem/thread)
__global__ __launch_bounds__(SCAN_B)
void scan_part(const int* __restrict__ cnt, int* __restrict__ off,
               int* __restrict__ bsum) {
  __shared__ int buf[SCAN_B];
  const int tid = threadIdx.x;
  const int i = blockIdx.x * SCAN_B + tid;
  const int v = (i < NN) ? cnt[i] : 0;
  buf[tid] = v;
  __syncthreads();
  for (int s = 1; s < SCAN_B; s <<= 1) {
    const int t = (tid >= s) ? buf[tid - s] : 0;
    __syncthreads();
    buf[tid] += t;
    __syncthreads();
  }
  if (i < NN) off[i] = buf[tid] - v;          // local exclusive
  if (tid == SCAN_B - 1) bsum[blockIdx.x] = buf[tid];
}

// phase 2: one wave scans the 40 block totals
__global__ __launch_bounds__(64)
void scan_tops(const int* __restrict__ bsum, int* __restrict__ boff,
               int* __restrict__ off) {
  const int tid = threadIdx.x;
  int v = (tid < SCAN_NB) ? bsum[tid] : 0;
  const int mine = v;
#pragma unroll
  for (int s = 1; s < 64; s <<= 1) {
    const int t = __shfl_up(v, s);
    if (tid >= s) v += t;
  }
  if (tid < SCAN_NB) boff[tid] = v - mine;    // exclusive
  if (tid == SCAN_NB - 1) off[NN] = v;        // grand total (= NE)
}

// phase 3: add block offsets, materialize off & cur
__global__ __launch_bounds__(SCAN_B)
void scan_add(int* __restrict__ off, const int* __restrict__ boff,
              int* __restrict__ cur) {
  const int i = blockIdx.x * SCAN_B + threadIdx.x;
  if (i < NN) {
    const int v = off[i] + boff[blockIdx.x];
    off[i] = v;
    cur[i] = v;
  }
}

__global__ void fill_k(const int* __restrict__ row, const int* __restrict__ col,
                       const float* __restrict__ w, int* __restrict__ cur,
                       int* __restrict__ esrc, float* __restrict__ ew) {
  const int e = blockIdx.x * blockDim.x + threadIdx.x;
  if (e < NE) {
    const int p = atomicAdd(&cur[col[e]], 1);
    esrc[p] = row[e];
    ew[p]   = w[e];
  }
}

// ---------------------------------------------------------------------------
// Gather (CSR) + PReLU: one wave per destination node; lane owns 2 columns.
// ---------------------------------------------------------------------------
__global__ __launch_bounds__(256)
void gather_prelu(const float* __restrict__ tmp, const int* __restrict__ off,
                  const int* __restrict__ esrc, const float* __restrict__ ew,
                  const float* __restrict__ aP, float* __restrict__ hout) {
  const int wid  = (blockIdx.x * 256 + threadIdx.x) >> 6;
  const int lane = threadIdx.x & 63;
  if (wid >= NN) return;
  const int lo = off[wid], hi = off[wid + 1];
  float ax = 0.f, ay = 0.f;
  int e = lo;
  for (; e + 1 < hi; e += 2) {
    const int   s0 = esrc[e],  s1 = esrc[e + 1];
    const float w0 = ew[e],    w1 = ew[e + 1];
    const float2 v0 = *(const float2*)(tmp + (size_t)s0 * D + lane * 2);
    const float2 v1 = *(const float2*)(tmp + (size_t)s1 * D + lane * 2);
    ax += v0.x * w0; ay += v0.y * w0;
    ax += v1.x * w1; ay += v1.y * w1;
  }
  if (e < hi) {
    const int s0 = esrc[e]; const float w0 = ew[e];
    const float2 v0 = *(const float2*)(tmp + (size_t)s0 * D + lane * 2);
    ax += v0.x * w0; ay += v0.y * w0;
  }
  const float alpha = aP[0];
  ax = ax >= 0.f ? ax : alpha * ax;
  ay = ay >= 0.f ? ay : alpha * ay;
  *(float2*)(hout + (size_t)wid * D + lane * 2) = make_float2(ax, ay);
}

// ---------------------------------------------------------------------------
// Graph pooling: block = 128 threads (one per column), grid = (NG, SPLIT).
// ---------------------------------------------------------------------------
constexpr int POOL_SPLIT = 8;

__device__ __forceinline__ int lbound(const int* a, int n, int key) {
  int lo = 0, hi = n;
  while (lo < hi) { const int m = (lo + hi) >> 1; if (a[m] < key) lo = m + 1; else hi = m; }
  return lo;
}

__global__ __launch_bounds__(128)
void pool_k(const float* __restrict__ h, const int* __restrict__ batch,
            float* __restrict__ hg, int layer) {
  const int g    = blockIdx.x;
  const int part = blockIdx.y;
  const int tid  = threadIdx.x;
  const int lo = lbound(batch, NN, g);
  const int hi = lbound(batch, NN, g + 1);
  float acc = 0.f;
  for (int n = lo + part; n < hi; n += POOL_SPLIT)
    acc += h[(size_t)n * D + tid];
  atomicAdd(&hg[(size_t)g * (3 * D) + layer * D + tid], acc);
}

// ---------------------------------------------------------------------------
extern "C" void kernel_launch(void* const* d_in, const int* in_sizes, int n_in,
                              void* d_out, int out_size, void* d_ws, size_t ws_size,
                              hipStream_t stream) {
  const float* feat    = (const float*)d_in[0];
  const float* eweight = (const float*)d_in[1];
  const float* W[3]    = {(const float*)d_in[2], (const float*)d_in[3], (const float*)d_in[4]};
  const float* a[3]    = {(const float*)d_in[5], (const float*)d_in[6], (const float*)d_in[7]};
  const int*   eidx    = (const int*)d_in[8];
  const int*   batch   = (const int*)d_in[9];
  const int*   erow = eidx;
  const int*   ecol = eidx + NE;

  char* ws = (char*)d_ws;
  float* tmp  = (float*)(ws);                 // 20,480,000 B
  float* hbuf = (float*)(ws + 20480000);      // 20,480,000 B
  int*   cnt  = (int*)(ws + 40960000);        //    163,840 B
  int*   off  = (int*)(ws + 41123840);        //    163,844 B
  int*   cur  = (int*)(ws + 41287744);        //    163,840 B
  int*   esrc = (int*)(ws + 41451584);        //  2,560,000 B
  float* ewr  = (float*)(ws + 44011584);      //  2,560,000 B
  int*   bsum = (int*)(ws + 46571584);        //        160 B
  int*   boff = (int*)(ws + 46571744);        //        160 B  (end ~46.6 MB)

  float* hout = (float*)d_out;                 // NN x D
  float* hg   = hout + (size_t)NN * D;         // NG x 3D

  hipMemsetAsync(cnt, 0, NN * sizeof(int), stream);
  hipMemsetAsync(hg, 0, (size_t)NG * 3 * D * sizeof(float), stream);

  hist_k<<<(NE + 255) / 256, 256, 0, stream>>>(ecol, cnt);
  scan_part<<<SCAN_NB, SCAN_B, 0, stream>>>(cnt, off, bsum);
  scan_tops<<<1, 64, 0, stream>>>(bsum, boff, off);
  scan_add<<<SCAN_NB, SCAN_B, 0, stream>>>(off, boff, cur);
  fill_k<<<(NE + 255) / 256, 256, 0, stream>>>(erow, ecol, eweight, cur, esrc, ewr);

  const float* in = feat;
  for (int l = 0; l < 3; ++l) {
    gemm_wt<<<NN / 64, 256, 0, stream>>>(in, W[l], tmp);
    float* dst = (l == 2) ? hout : hbuf;
    gather_prelu<<<(NN * 64) / 256, 256, 0, stream>>>(tmp, off, esrc, ewr, a[l], dst);
    pool_k<<<dim3(NG, POOL_SPLIT), 128, 0, stream>>>(dst, batch, hg, l);
    in = dst;
  }
}

// Round 5
// 408.311 us; speedup vs baseline: 1.3246x; 1.0916x over previous
//
#include <hip/hip_runtime.h>
#include <hip/hip_bf16.h>

constexpr int NN = 40000;
constexpr int NE = 640000;
constexpr int D  = 128;
constexpr int NG = 128;

__device__ __forceinline__ ushort f2bf(float x) {
  union { float f; unsigned u; } c{x};
  const unsigned r = (c.u + 0x7FFFu + ((c.u >> 16) & 1u)) >> 16;  // RNE
  return (ushort)r;
}

// ---------------------------------------------------------------------------
// GEMM: out[n][d] = sum_k A[n][k] * W[d][k]   (h = A @ W^T), bf16 output.
// block = 256 threads = 16 row-quads x 16 d-slices(8); 64 rows per block.
// ---------------------------------------------------------------------------
__global__ __launch_bounds__(256)
void gemm_wt(const float* __restrict__ A, const float* __restrict__ W,
             ushort* __restrict__ out) {
  __shared__ float wt[128 * 132];
  const int tid = threadIdx.x;
  for (int i = tid; i < 128 * 128; i += 256) {
    const int d = i >> 7, k = i & 127;
    wt[k * 132 + d] = W[i];
  }
  __syncthreads();

  const int s  = tid & 15;          // d-slice index
  const int rq = tid >> 4;          // row-quad index
  const int n0 = blockIdx.x * 64 + rq * 4;
  const int d0 = s * 8;
  const float* ap = A + (size_t)n0 * D;

  float acc[4][8];
#pragma unroll
  for (int r = 0; r < 4; ++r)
#pragma unroll
    for (int j = 0; j < 8; ++j) acc[r][j] = 0.f;

  for (int kc = 0; kc < 32; ++kc) {
    float av[4][4];
#pragma unroll
    for (int r = 0; r < 4; ++r)
      *(float4*)av[r] = *(const float4*)(ap + (size_t)r * D + kc * 4);
#pragma unroll
    for (int kk = 0; kk < 4; ++kk) {
      const float* wrow = &wt[(kc * 4 + kk) * 132 + d0];
      const float4 w0 = *(const float4*)(wrow);
      const float4 w1 = *(const float4*)(wrow + 4);
#pragma unroll
      for (int r = 0; r < 4; ++r) {
        const float a = av[r][kk];
        acc[r][0] += a * w0.x; acc[r][1] += a * w0.y;
        acc[r][2] += a * w0.z; acc[r][3] += a * w0.w;
        acc[r][4] += a * w1.x; acc[r][5] += a * w1.y;
        acc[r][6] += a * w1.z; acc[r][7] += a * w1.w;
      }
    }
  }
#pragma unroll
  for (int r = 0; r < 4; ++r) {
    union { uint4 u4; ushort us[8]; } pk;
#pragma unroll
    for (int j = 0; j < 8; ++j) pk.us[j] = f2bf(acc[r][j]);
    *(uint4*)(out + (size_t)(n0 + r) * D + d0) = pk.u4;
  }
}

// ---------------------------------------------------------------------------
// CSR build: histogram, 3-phase parallel scan, packed fill (uint2 per edge).
// ---------------------------------------------------------------------------
__global__ void hist_k(const int* __restrict__ col, int* __restrict__ cnt) {
  const int e = blockIdx.x * blockDim.x + threadIdx.x;
  if (e < NE) atomicAdd(&cnt[col[e]], 1);
}

constexpr int SCAN_B = 1024;
constexpr int SCAN_NB = (NN + SCAN_B - 1) / SCAN_B;  // 40

__global__ __launch_bounds__(SCAN_B)
void scan_part(const int* __restrict__ cnt, int* __restrict__ off,
               int* __restrict__ bsum) {
  __shared__ int buf[SCAN_B];
  const int tid = threadIdx.x;
  const int i = blockIdx.x * SCAN_B + tid;
  const int v = (i < NN) ? cnt[i] : 0;
  buf[tid] = v;
  __syncthreads();
  for (int s = 1; s < SCAN_B; s <<= 1) {
    const int t = (tid >= s) ? buf[tid - s] : 0;
    __syncthreads();
    buf[tid] += t;
    __syncthreads();
  }
  if (i < NN) off[i] = buf[tid] - v;
  if (tid == SCAN_B - 1) bsum[blockIdx.x] = buf[tid];
}

__global__ __launch_bounds__(64)
void scan_tops(const int* __restrict__ bsum, int* __restrict__ boff,
               int* __restrict__ off) {
  const int tid = threadIdx.x;
  int v = (tid < SCAN_NB) ? bsum[tid] : 0;
  const int mine = v;
#pragma unroll
  for (int s = 1; s < 64; s <<= 1) {
    const int t = __shfl_up(v, s);
    if (tid >= s) v += t;
  }
  if (tid < SCAN_NB) boff[tid] = v - mine;
  if (tid == SCAN_NB - 1) off[NN] = v;
}

__global__ __launch_bounds__(SCAN_B)
void scan_add(int* __restrict__ off, const int* __restrict__ boff,
              int* __restrict__ cur) {
  const int i = blockIdx.x * SCAN_B + threadIdx.x;
  if (i < NN) {
    const int v = off[i] + boff[blockIdx.x];
    off[i] = v;
    cur[i] = v;
  }
}

__global__ void fill_k(const int* __restrict__ row, const int* __restrict__ col,
                       const float* __restrict__ w, int* __restrict__ cur,
                       uint2* __restrict__ epk) {
  const int e = blockIdx.x * blockDim.x + threadIdx.x;
  if (e < NE) {
    const int p = atomicAdd(&cur[col[e]], 1);
    uint2 v;
    v.x = (unsigned)row[e];
    v.y = __float_as_uint(w[e]);
    epk[p] = v;
  }
}

// ---------------------------------------------------------------------------
// Gather (CSR, bf16 rows) + PReLU: one wave per destination node.
// Each lane owns 2 columns (one dword = 2 bf16 per row read).
// ---------------------------------------------------------------------------
__global__ __launch_bounds__(256)
void gather_prelu(const ushort* __restrict__ tmp, const int* __restrict__ off,
                  const uint2* __restrict__ epk,
                  const float* __restrict__ aP, float* __restrict__ hout) {
  const int wid  = (blockIdx.x * 256 + threadIdx.x) >> 6;
  const int lane = threadIdx.x & 63;
  if (wid >= NN) return;
  const int lo = off[wid], hi = off[wid + 1];
  float ax = 0.f, ay = 0.f;
  int e = lo;
  for (; e + 1 < hi; e += 2) {
    const uint2 e0 = epk[e], e1 = epk[e + 1];
    const float w0 = __uint_as_float(e0.y), w1 = __uint_as_float(e1.y);
    const unsigned v0 = *(const unsigned*)(tmp + (size_t)e0.x * D + lane * 2);
    const unsigned v1 = *(const unsigned*)(tmp + (size_t)e1.x * D + lane * 2);
    ax += __uint_as_float(v0 << 16) * w0;
    ay += __uint_as_float(v0 & 0xFFFF0000u) * w0;
    ax += __uint_as_float(v1 << 16) * w1;
    ay += __uint_as_float(v1 & 0xFFFF0000u) * w1;
  }
  if (e < hi) {
    const uint2 e0 = epk[e];
    const float w0 = __uint_as_float(e0.y);
    const unsigned v0 = *(const unsigned*)(tmp + (size_t)e0.x * D + lane * 2);
    ax += __uint_as_float(v0 << 16) * w0;
    ay += __uint_as_float(v0 & 0xFFFF0000u) * w0;
  }
  const float alpha = aP[0];
  ax = ax >= 0.f ? ax : alpha * ax;
  ay = ay >= 0.f ? ay : alpha * ay;
  *(float2*)(hout + (size_t)wid * D + lane * 2) = make_float2(ax, ay);
}

// ---------------------------------------------------------------------------
// Graph pooling: block = 128 threads (one per column), grid = (NG, SPLIT).
// ---------------------------------------------------------------------------
constexpr int POOL_SPLIT = 8;

__device__ __forceinline__ int lbound(const int* a, int n, int key) {
  int lo = 0, hi = n;
  while (lo < hi) { const int m = (lo + hi) >> 1; if (a[m] < key) lo = m + 1; else hi = m; }
  return lo;
}

__global__ __launch_bounds__(128)
void pool_k(const float* __restrict__ h, const int* __restrict__ batch,
            float* __restrict__ hg, int layer) {
  const int g    = blockIdx.x;
  const int part = blockIdx.y;
  const int tid  = threadIdx.x;
  const int lo = lbound(batch, NN, g);
  const int hi = lbound(batch, NN, g + 1);
  float acc = 0.f;
  for (int n = lo + part; n < hi; n += POOL_SPLIT)
    acc += h[(size_t)n * D + tid];
  atomicAdd(&hg[(size_t)g * (3 * D) + layer * D + tid], acc);
}

// ---------------------------------------------------------------------------
extern "C" void kernel_launch(void* const* d_in, const int* in_sizes, int n_in,
                              void* d_out, int out_size, void* d_ws, size_t ws_size,
                              hipStream_t stream) {
  const float* feat    = (const float*)d_in[0];
  const float* eweight = (const float*)d_in[1];
  const float* W[3]    = {(const float*)d_in[2], (const float*)d_in[3], (const float*)d_in[4]};
  const float* a[3]    = {(const float*)d_in[5], (const float*)d_in[6], (const float*)d_in[7]};
  const int*   eidx    = (const int*)d_in[8];
  const int*   batch   = (const int*)d_in[9];
  const int*   erow = eidx;
  const int*   ecol = eidx + NE;

  char* ws = (char*)d_ws;
  ushort* tmp  = (ushort*)(ws);               // 10,240,000 B (bf16 NN x D)
  float*  hbuf = (float*)(ws + 10240000);     // 20,480,000 B
  int*    cnt  = (int*)(ws + 30720000);       //    160,000 B
  int*    off  = (int*)(ws + 30880000);       //    160,004 B
  int*    cur  = (int*)(ws + 31040064);       //    160,000 B
  uint2*  epk  = (uint2*)(ws + 31200064);     //  5,120,000 B
  int*    bsum = (int*)(ws + 36320064);       //        160 B
  int*    boff = (int*)(ws + 36320224);       //        160 B  (end ~36.3 MB)

  float* hout = (float*)d_out;                 // NN x D
  float* hg   = hout + (size_t)NN * D;         // NG x 3D

  hipMemsetAsync(cnt, 0, NN * sizeof(int), stream);
  hipMemsetAsync(hg, 0, (size_t)NG * 3 * D * sizeof(float), stream);

  hist_k<<<(NE + 255) / 256, 256, 0, stream>>>(ecol, cnt);
  scan_part<<<SCAN_NB, SCAN_B, 0, stream>>>(cnt, off, bsum);
  scan_tops<<<1, 64, 0, stream>>>(bsum, boff, off);
  scan_add<<<SCAN_NB, SCAN_B, 0, stream>>>(off, boff, cur);
  fill_k<<<(NE + 255) / 256, 256, 0, stream>>>(erow, ecol, eweight, cur, epk);

  const float* in = feat;
  for (int l = 0; l < 3; ++l) {
    gemm_wt<<<NN / 64, 256, 0, stream>>>(in, W[l], tmp);
    float* dst = (l == 2) ? hout : hbuf;
    gather_prelu<<<(NN * 64) / 256, 256, 0, stream>>>(tmp, off, epk, a[l], dst);
    pool_k<<<dim3(NG, POOL_SPLIT), 128, 0, stream>>>(dst, batch, hg, l);
    in = dst;
  }
}

// Round 6
// 334.198 us; speedup vs baseline: 1.6183x; 1.2218x over previous
//
#include <hip/hip_runtime.h>
#include <hip/hip_bf16.h>

constexpr int NN = 40000;
constexpr int NE = 640000;
constexpr int D  = 128;
constexpr int NG = 128;

__device__ __forceinline__ ushort f2bf(float x) {
  union { float f; unsigned u; } c{x};
  const unsigned r = (c.u + 0x7FFFu + ((c.u >> 16) & 1u)) >> 16;  // RNE
  return (ushort)r;
}
__device__ __forceinline__ float bf2f(ushort b) {
  return __uint_as_float(((unsigned)b) << 16);
}

// ---------------------------------------------------------------------------
// Converters: f32 -> bf16 (vectorized float4 -> ushort4)
// ---------------------------------------------------------------------------
__global__ void cvt_feat(const float* __restrict__ f, ushort* __restrict__ o,
                         int n4) {
  const int i = blockIdx.x * blockDim.x + threadIdx.x;
  if (i < n4) {
    const float4 v = ((const float4*)f)[i];
    union { ushort4 u; } p;
    p.u.x = f2bf(v.x); p.u.y = f2bf(v.y); p.u.z = f2bf(v.z); p.u.w = f2bf(v.w);
    ((ushort4*)o)[i] = p.u;
  }
}

__global__ void cvt_w(const float* __restrict__ w0, const float* __restrict__ w1,
                      const float* __restrict__ w2, ushort* __restrict__ o) {
  const float* src = blockIdx.y == 0 ? w0 : (blockIdx.y == 1 ? w1 : w2);
  ushort* dst = o + (size_t)blockIdx.y * D * D;
  const int i = blockIdx.x * blockDim.x + threadIdx.x;  // float4 index, n4=4096
  if (i < D * D / 4) {
    const float4 v = ((const float4*)src)[i];
    union { ushort4 u; } p;
    p.u.x = f2bf(v.x); p.u.y = f2bf(v.y); p.u.z = f2bf(v.z); p.u.w = f2bf(v.w);
    ((ushort4*)dst)[i] = p.u;
  }
}

// ---------------------------------------------------------------------------
// MFMA GEMM: tmp[n][d] = sum_k A[n][k] * W[d][k], all bf16 in, bf16 out.
// 256 thr = 4 waves, 16 rows/wave, 64 rows/block. Fragments loaded directly
// from global: A lane l -> row (l&15), k = (l>>4)*8.. (16B contiguous);
// B (=W^T) lane l -> W row (l&15 within col-tile), same 16B pattern.
// C/D: col=lane&15, row=(lane>>4)*4+reg (m89-verified).
// ---------------------------------------------------------------------------
using short8 = __attribute__((ext_vector_type(8))) short;
using f32x4  = __attribute__((ext_vector_type(4))) float;

__global__ __launch_bounds__(256)
void gemm_mfma(const ushort* __restrict__ A, const ushort* __restrict__ Wb,
               ushort* __restrict__ out) {
  const int tid  = threadIdx.x;
  const int wave = tid >> 6, lane = tid & 63;
  const int n0 = blockIdx.x * 64 + wave * 16;
  const int r  = lane & 15, kg = lane >> 4;

  short8 afr[4];
  const ushort* arow = A + (size_t)(n0 + r) * D + kg * 8;
#pragma unroll
  for (int kt = 0; kt < 4; ++kt)
    afr[kt] = *(const short8*)(arow + kt * 32);

#pragma unroll
  for (int ct = 0; ct < 8; ++ct) {
    f32x4 acc = {0.f, 0.f, 0.f, 0.f};
    const ushort* wrow = Wb + (size_t)(ct * 16 + r) * D + kg * 8;
#pragma unroll
    for (int kt = 0; kt < 4; ++kt) {
      const short8 bfr = *(const short8*)(wrow + kt * 32);
      acc = __builtin_amdgcn_mfma_f32_16x16x32_bf16(afr[kt], bfr, acc, 0, 0, 0);
    }
#pragma unroll
    for (int q = 0; q < 4; ++q) {
      const int m = kg * 4 + q;                 // row within 16-row tile
      out[(size_t)(n0 + m) * D + ct * 16 + r] = f2bf(acc[q]);
    }
  }
}

// ---------------------------------------------------------------------------
// CSR build: histogram, 3-phase parallel scan, packed fill (uint2 per edge).
// ---------------------------------------------------------------------------
__global__ void hist_k(const int* __restrict__ col, int* __restrict__ cnt) {
  const int e = blockIdx.x * blockDim.x + threadIdx.x;
  if (e < NE) atomicAdd(&cnt[col[e]], 1);
}

constexpr int SCAN_B = 1024;
constexpr int SCAN_NB = (NN + SCAN_B - 1) / SCAN_B;  // 40

__global__ __launch_bounds__(SCAN_B)
void scan_part(const int* __restrict__ cnt, int* __restrict__ off,
               int* __restrict__ bsum) {
  __shared__ int buf[SCAN_B];
  const int tid = threadIdx.x;
  const int i = blockIdx.x * SCAN_B + tid;
  const int v = (i < NN) ? cnt[i] : 0;
  buf[tid] = v;
  __syncthreads();
  for (int s = 1; s < SCAN_B; s <<= 1) {
    const int t = (tid >= s) ? buf[tid - s] : 0;
    __syncthreads();
    buf[tid] += t;
    __syncthreads();
  }
  if (i < NN) off[i] = buf[tid] - v;
  if (tid == SCAN_B - 1) bsum[blockIdx.x] = buf[tid];
}

__global__ __launch_bounds__(64)
void scan_tops(const int* __restrict__ bsum, int* __restrict__ boff,
               int* __restrict__ off) {
  const int tid = threadIdx.x;
  int v = (tid < SCAN_NB) ? bsum[tid] : 0;
  const int mine = v;
#pragma unroll
  for (int s = 1; s < 64; s <<= 1) {
    const int t = __shfl_up(v, s);
    if (tid >= s) v += t;
  }
  if (tid < SCAN_NB) boff[tid] = v - mine;
  if (tid == SCAN_NB - 1) off[NN] = v;
}

__global__ __launch_bounds__(SCAN_B)
void scan_add(int* __restrict__ off, const int* __restrict__ boff,
              int* __restrict__ cur) {
  const int i = blockIdx.x * SCAN_B + threadIdx.x;
  if (i < NN) {
    const int v = off[i] + boff[blockIdx.x];
    off[i] = v;
    cur[i] = v;
  }
}

__global__ void fill_k(const int* __restrict__ row, const int* __restrict__ col,
                       const float* __restrict__ w, int* __restrict__ cur,
                       uint2* __restrict__ epk) {
  const int e = blockIdx.x * blockDim.x + threadIdx.x;
  if (e < NE) {
    const int p = atomicAdd(&cur[col[e]], 1);
    uint2 v;
    v.x = (unsigned)row[e];
    v.y = __float_as_uint(w[e]);
    epk[p] = v;
  }
}

// ---------------------------------------------------------------------------
// Gather (CSR, bf16 rows) + PReLU, MLP-restructured:
// - one wave per node; lane i cooperatively loads edge-meta epk[lo+i]
// - src/weight broadcast via v_readlane (wave-uniform SGPRs)
// - row loads issued in batches of 8 independent gathers
// - tail padded with (src=0, w=0): dummy loads hit tmp row 0 (L1), add 0.
// Writes bf16 h (always) + f32 h (final layer only).
// ---------------------------------------------------------------------------
__global__ __launch_bounds__(256)
void gather_prelu(const ushort* __restrict__ tmp, const int* __restrict__ off,
                  const uint2* __restrict__ epk, const float* __restrict__ aP,
                  ushort* __restrict__ hb, float* __restrict__ hout) {
  const int wid  = (blockIdx.x * 256 + threadIdx.x) >> 6;
  const int lane = threadIdx.x & 63;
  if (wid >= NN) return;
  const int lo = off[wid], hi = off[wid + 1];
  const int deg = hi - lo;
  float ax = 0.f, ay = 0.f;

  for (int base = 0; base < deg; base += 64) {
    const int rem = deg - base;
    uint2 meta = make_uint2(0u, 0u);
    if (lane < rem) meta = epk[lo + base + lane];
    const int cnt = rem < 64 ? rem : 64;
    for (int j0 = 0; j0 < cnt; j0 += 8) {
      unsigned v[8]; float w[8];
#pragma unroll
      for (int j = 0; j < 8; ++j) {
        const int src = __builtin_amdgcn_readlane((int)meta.x, j0 + j);
        w[j] = __uint_as_float(__builtin_amdgcn_readlane((int)meta.y, j0 + j));
        v[j] = *(const unsigned*)(tmp + (size_t)src * D + lane * 2);
      }
#pragma unroll
      for (int j = 0; j < 8; ++j) {
        ax += __uint_as_float(v[j] << 16) * w[j];
        ay += __uint_as_float(v[j] & 0xFFFF0000u) * w[j];
      }
    }
  }
  const float alpha = aP[0];
  ax = ax >= 0.f ? ax : alpha * ax;
  ay = ay >= 0.f ? ay : alpha * ay;
  union { unsigned u; ushort s[2]; } pk;
  pk.s[0] = f2bf(ax); pk.s[1] = f2bf(ay);
  *(unsigned*)(hb + (size_t)wid * D + lane * 2) = pk.u;
  if (hout)
    *(float2*)(hout + (size_t)wid * D + lane * 2) = make_float2(ax, ay);
}

// ---------------------------------------------------------------------------
// Graph pooling from bf16 h: block = 128 threads (one per column).
// ---------------------------------------------------------------------------
constexpr int POOL_SPLIT = 8;

__device__ __forceinline__ int lbound(const int* a, int n, int key) {
  int lo = 0, hi = n;
  while (lo < hi) { const int m = (lo + hi) >> 1; if (a[m] < key) lo = m + 1; else hi = m; }
  return lo;
}

__global__ __launch_bounds__(128)
void pool_k(const ushort* __restrict__ h, const int* __restrict__ batch,
            float* __restrict__ hg, int layer) {
  const int g    = blockIdx.x;
  const int part = blockIdx.y;
  const int tid  = threadIdx.x;
  const int lo = lbound(batch, NN, g);
  const int hi = lbound(batch, NN, g + 1);
  float acc = 0.f;
  for (int n = lo + part; n < hi; n += POOL_SPLIT)
    acc += bf2f(h[(size_t)n * D + tid]);
  atomicAdd(&hg[(size_t)g * (3 * D) + layer * D + tid], acc);
}

// ---------------------------------------------------------------------------
extern "C" void kernel_launch(void* const* d_in, const int* in_sizes, int n_in,
                              void* d_out, int out_size, void* d_ws, size_t ws_size,
                              hipStream_t stream) {
  const float* feat    = (const float*)d_in[0];
  const float* eweight = (const float*)d_in[1];
  const float* W[3]    = {(const float*)d_in[2], (const float*)d_in[3], (const float*)d_in[4]};
  const float* a[3]    = {(const float*)d_in[5], (const float*)d_in[6], (const float*)d_in[7]};
  const int*   eidx    = (const int*)d_in[8];
  const int*   batch   = (const int*)d_in[9];
  const int*   erow = eidx;
  const int*   ecol = eidx + NE;

  char* ws = (char*)d_ws;
  ushort* tmp   = (ushort*)(ws);               // 10,240,000 B (bf16 NN x D)
  ushort* hb    = (ushort*)(ws + 10240000);    // 10,240,000 B (bf16 h)
  ushort* featb = (ushort*)(ws + 20480000);    // 10,240,000 B (bf16 feat)
  int*    cnt   = (int*)(ws + 30720000);       //    160,000 B
  int*    off   = (int*)(ws + 30880000);       //    160,004 B
  int*    cur   = (int*)(ws + 31040064);       //    160,000 B
  uint2*  epk   = (uint2*)(ws + 31200064);     //  5,120,000 B
  int*    bsum  = (int*)(ws + 36320064);       //        160 B
  int*    boff  = (int*)(ws + 36320224);       //        160 B
  ushort* Wb    = (ushort*)(ws + 36320384);    //     98,304 B  (3 x 128 x 128)

  float* hout = (float*)d_out;                 // NN x D (f32)
  float* hg   = hout + (size_t)NN * D;         // NG x 3D

  hipMemsetAsync(cnt, 0, NN * sizeof(int), stream);
  hipMemsetAsync(hg, 0, (size_t)NG * 3 * D * sizeof(float), stream);

  hist_k<<<(NE + 255) / 256, 256, 0, stream>>>(ecol, cnt);
  scan_part<<<SCAN_NB, SCAN_B, 0, stream>>>(cnt, off, bsum);
  scan_tops<<<1, 64, 0, stream>>>(bsum, boff, off);
  scan_add<<<SCAN_NB, SCAN_B, 0, stream>>>(off, boff, cur);
  fill_k<<<(NE + 255) / 256, 256, 0, stream>>>(erow, ecol, eweight, cur, epk);

  cvt_feat<<<(NN * D / 4 + 255) / 256, 256, 0, stream>>>(feat, featb, NN * D / 4);
  cvt_w<<<dim3((D * D / 4 + 255) / 256, 3), 256, 0, stream>>>(W[0], W[1], W[2], Wb);

  const ushort* in = featb;
  for (int l = 0; l < 3; ++l) {
    gemm_mfma<<<NN / 64, 256, 0, stream>>>(in, Wb + (size_t)l * D * D, tmp);
    gather_prelu<<<(NN * 64 + 255) / 256, 256, 0, stream>>>(
        tmp, off, epk, a[l], hb, (l == 2) ? hout : nullptr);
    pool_k<<<dim3(NG, POOL_SPLIT), 128, 0, stream>>>(hb, batch, hg, l);
    in = hb;
  }
}